// Round 6
// baseline (407.914 us; speedup 1.0000x reference)
//
#include <hip/hip_runtime.h>
#include <hip/hip_bf16.h>

#define DF   128      // feature dim
#define DPC  16       // dims per capsule (8 caps)
#define KCAP 64       // slots per 128B row (count lives in separate cnt array)
#define RWU  64       // ushorts per slot row

#define NB_PREP  2048 // persistent prep WGs (fused xc + bucket)
#define NB_ROUTE 1792 // 7 WG/CU x 256 CU (waves_per_eu(7) -> 72-VGPR tier)
#define NB_ZERO  64   // detect (1) + cnt zeroing (63)

// ---------- helpers ----------
__device__ __forceinline__ float cap_sum(float v) {   // sum over lanes l..l|7
    v += __shfl_xor(v, 1);
    v += __shfl_xor(v, 2);
    v += __shfl_xor(v, 4);
    return v;
}
__device__ __forceinline__ float bits_lo(unsigned int w) {
    union { unsigned int u; float f; } c; c.u = w << 16; return c.f;
}
__device__ __forceinline__ float bits_hi(unsigned int w) {
    union { unsigned int u; float f; } c; c.u = w & 0xFFFF0000u; return c.f;
}
__device__ __forceinline__ unsigned int f2b_pack(float lo, float hi) {
    __hip_bfloat16 a = __float2bfloat16(lo), b = __float2bfloat16(hi);
    unsigned short ua = *reinterpret_cast<unsigned short*>(&a);
    unsigned short ub = *reinterpret_cast<unsigned short*>(&b);
    return ((unsigned int)ub << 16) | ua;
}
__device__ __forceinline__ float2 load_x2(const void* __restrict__ xraw, int fp32,
                                          int node, int lane) {
    size_t off = (size_t)node * DF + (size_t)lane * 2;
    if (fp32) {
        return *reinterpret_cast<const float2*>((const float*)xraw + off);
    } else {
        unsigned int w = ((const unsigned int*)xraw)[(size_t)node * 64 + lane];
        return make_float2(bits_lo(w), bits_hi(w));
    }
}
// per-chunk routing math on PACKED bf16 words (each word unpacked twice ->
// fewer live VGPRs; keeps the kernel under the waves_per_eu(7)/72-VGPR cap
// with zero scratch). softmax groups = 8 lanes sharing bits 3..5 (slot+half),
// i.e. xor 1,2,4 -- valid in both the 8-slot and the 2-node/4-slot layouts.
__device__ __forceinline__ void proc_pk(const uint4& w0, const uint4& w1,
                                        bool valid, const float* u, float* acc) {
    unsigned ww[8] = {w0.x, w0.y, w0.z, w0.w, w1.x, w1.y, w1.z, w1.w};
    float p = 0.0f;
    #pragma unroll
    for (int q = 0; q < 8; ++q) {
        p = fmaf(bits_lo(ww[q]), u[2*q],   p);
        p = fmaf(bits_hi(ww[q]), u[2*q+1], p);
    }
    float ex = __expf(p);
    float sd = ex;
    sd += __shfl_xor(sd, 1);
    sd += __shfl_xor(sd, 2);
    sd += __shfl_xor(sd, 4);
    float w = valid ? ex * __builtin_amdgcn_rcpf(sd) : 0.0f;
    #pragma unroll
    for (int q = 0; q < 8; ++q) {
        acc[2*q]   = fmaf(w, bits_lo(ww[q]), acc[2*q]);
        acc[2*q+1] = fmaf(w, bits_hi(ww[q]), acc[2*q+1]);
    }
}

// ---------- 1: detect dtypes (block 0) + zero cnt array (blocks 1..) --------
__global__ void k_detect_zero(const unsigned int* __restrict__ xw,
                              const unsigned int* __restrict__ ew,
                              int* __restrict__ flags, int* __restrict__ cnt,
                              int zwords) {
    if (blockIdx.x == 0) {
        __shared__ int s_nan, s_zero;
        int tid = threadIdx.x;
        if (tid == 0) { s_nan = 0; s_zero = 0; }
        __syncthreads();
        int cnt_nan = 0;
        for (int i = tid; i < 4096; i += 256) {       // P(fp32 miss) ~ e^-16
            unsigned int lo = xw[i] & 0xFFFFu;
            if ((lo & 0x7F80u) == 0x7F80u) cnt_nan++; // impossible in bf16 data
        }
        int cnt_zero = 0;
        for (int i = tid; i < 1024; i += 256) {
            if (ew[2 * i + 1] == 0u) cnt_zero++;      // int64 high words zero
        }
        atomicAdd(&s_nan, cnt_nan);
        atomicAdd(&s_zero, cnt_zero);
        __syncthreads();
        if (tid == 0) {
            flags[0] = (s_nan > 0) ? 1 : 0;   // x is fp32
            flags[1] = (s_zero > 512) ? 1 : 0; // edge_index is int64
        }
    } else {
        int stride = (NB_ZERO - 1) * 256;
        for (int i = (blockIdx.x - 1) * 256 + threadIdx.x; i < zwords; i += stride)
            cnt[i] = 0;
    }
}

// ---------- 2: FUSED xc(bf16, swizzled) + bucketing -------------------------
// Re-fused (r5's split cost ~15us of lost overlap: the xc math hides under
// the bucket phase's atomic latency). cnt/rows stay separated (r5 layout;
// neutral vs combined, and rows need no zeroing).
// xc row (256 B): words [0,32) = caps' dims 0..7, words [32,64) = dims 8..15.
__global__ void k_prep(const void* __restrict__ xraw, unsigned int* __restrict__ xcb,
                       const int* __restrict__ ei,
                       int* __restrict__ cnt, int cstr,
                       unsigned short* __restrict__ rows,
                       const int* __restrict__ flags,
                       int n_nodes, int n_edges) {
    const int fp32 = flags[0];
    const int lane = threadIdx.x & 63;
    const int gw   = (blockIdx.x * blockDim.x + threadIdx.x) >> 6;
    const int nw   = (gridDim.x * blockDim.x) >> 6;
    for (int wid = gw; wid < n_nodes; wid += nw) {
        float2 v = load_x2(xraw, fp32, wid, lane);
        float ss = cap_sum(v.x * v.x + v.y * v.y);
        float scale = 1.0f / fmaxf(sqrtf(ss), 1e-12f);
        int cc = lane >> 3, jp = lane & 7;
        int w = (jp < 4) ? (cc * 4 + jp) : (32 + cc * 4 + (jp - 4));
        xcb[(size_t)wid * 64 + w] = f2b_pack(v.x * scale, v.y * scale);
    }

    const int i64 = flags[1];
    const int gtid = blockIdx.x * blockDim.x + threadIdx.x;
    const int gth  = gridDim.x * blockDim.x;
    for (int e = gtid; e < n_edges; e += gth) {
        int s, t;
        if (i64) {   // coalesced 8B loads, keep low words
            s = (int)((const long long*)ei)[e];
            t = (int)((const long long*)ei)[(size_t)n_edges + e];
        } else {
            s = ei[e]; t = ei[(size_t)n_edges + e];
        }
        if ((unsigned)s < (unsigned)n_nodes && (unsigned)t < (unsigned)n_nodes) {
            int slot = atomicAdd(cnt + (size_t)t * cstr, 1);
            if (slot < KCAP)
                rows[(size_t)t * KCAP + slot] = (unsigned short)s;
        }
    }
}

// ---------- 3: fused 3-iteration routing, TWO nodes per wave ----------------
// Round-6 structure. Lane = half*32 + slot*8 + cap: half A = node 2p (lanes
// 0..31), half B = node 2p+1 (lanes 32..63); 4 edge slots x 8 caps per node.
// Why: the per-ITERATION fixed costs (acc reduce + residual/norm, ~186 instr)
// were ~45% of route VALU at deg~16 and are per-WAVE, not per-edge. With two
// nodes per wave every fixed-cost instruction serves both nodes, and the acc
// reduce drops from 3 shfl levels (xor8,16,32) to 2 (xor8,16). Chunk math
// cost per edge is unchanged (still 8 edges per proc_pk call: 4+4).
// Loads: chunks reloaded from global each iteration (xcb is LLC-resident) --
// r1/r3 (reg cache) spilled, r5 (LDS cache) lost occupancy; r2's reload
// structure was the best and this keeps it. waves_per_eu(7) caps VGPR at 72
// (estimated peak ~68) so nothing spills, at 7 waves/SIMD.
__global__ void __launch_bounds__(256)
__attribute__((amdgpu_waves_per_eu(7)))
k_route(const unsigned short* __restrict__ rows,
        const unsigned int* __restrict__ xcb,
        const int* __restrict__ cnt, int cstr,
        float* __restrict__ u_out, int n_nodes) {
    const int lane = threadIdx.x & 63;
    const int hl   = lane & 31;          // lane within half
    const int sl   = (lane >> 3) & 3;    // slot 0..3
    const int c    = lane & 7;           // capsule
    const int coff = c * 16;             // byte offset within each 128 B half
    const char* __restrict__ xb = (const char*)xcb;
    const int gw = (blockIdx.x * blockDim.x + threadIdx.x) >> 6;
    const int nw = (gridDim.x * blockDim.x) >> 6;
    const int npair = (n_nodes + 1) >> 1;
    const int nmax  = n_nodes - 1;

    for (int pr = gw; pr < npair; pr += nw) {
        int  tA  = pr * 2;
        bool wrB = (tA + 1) < n_nodes;
        int  t   = (lane >= 32 && wrB) ? tA + 1 : tA;  // B falls back to A

        // each half loads its node's full 128B slot row (32 dwords)
        unsigned rw = ((const unsigned*)(rows + (size_t)t * RWU))[hl];
        int deg = cnt[(size_t)t * cstr];               // uniform within half
        deg = min(deg, KCAP);

        // target row
        size_t trow = (size_t)t << 8;
        uint4 t0 = *reinterpret_cast<const uint4*>(xb + trow + coff);
        uint4 t1 = *reinterpret_cast<const uint4*>(xb + trow + 128 + coff);

        // wave-uniform chunk count = max over the two halves
        int dm = max(deg, __shfl_xor(deg, 32));
        int km = __builtin_amdgcn_readfirstlane((dm + 3) >> 2);

        // slot s ushort: dword s>>1 of the half's row, half-sel s&1
        auto nid = [&](int s) -> int {
            unsigned wv = __shfl(rw, (lane & 32) | (s >> 1));
            int id = (int)((s & 1) ? (wv >> 16) : (wv & 0xFFFFu));
            return min(id, nmax);    // clamp garbage (deg==0 rows) in-bounds
        };
        // per-lane offsets for the first 4 chunks (16 edges), computed once
        int s0 = sl,      off0 = (deg > 0)  ? (nid(s0 < deg ? s0 : 0) << 8) : 0;
        int s1 = sl + 4,  off1 = (deg > 4)  ? (nid(s1 < deg ? s1 : 0) << 8) : 0;
        int s2 = sl + 8,  off2 = (deg > 8)  ? (nid(s2 < deg ? s2 : 0) << 8) : 0;
        int s3 = sl + 12, off3 = (deg > 12) ? (nid(s3 < deg ? s3 : 0) << 8) : 0;

        // normalize target capsule (packed tw[] + sc; xt recomputed on use)
        unsigned tw[8] = {t0.x, t0.y, t0.z, t0.w, t1.x, t1.y, t1.z, t1.w};
        float ss = 0.0f;
        #pragma unroll
        for (int q = 0; q < 8; ++q) {
            float xl = bits_lo(tw[q]), xh = bits_hi(tw[q]);
            ss = fmaf(xl, xl, ss);
            ss = fmaf(xh, xh, ss);
        }
        float sc = __builtin_amdgcn_rsqf(fmaxf(ss, 1e-24f));
        float u[DPC];
        #pragma unroll
        for (int q = 0; q < 8; ++q) {
            u[2*q]   = bits_lo(tw[q]) * sc;
            u[2*q+1] = bits_hi(tw[q]) * sc;
        }

        for (int it = 0; it < 3; ++it) {
            // stop load-CSE across iterations (reg-cached chunks would spill,
            // r1/r3) and force tail nid shfls to recompute (reg pressure)
            asm volatile("" : "+v"(rw));
            asm volatile("" ::: "memory");

            float acc[DPC];
            #pragma unroll
            for (int j = 0; j < DPC; ++j) acc[j] = 0.0f;

            uint4 a0, b0, a1, b1;
            if (km > 0) {       // issue chunks 0,1 back-to-back
                a0 = *reinterpret_cast<const uint4*>(xb + off0 + coff);
                b0 = *reinterpret_cast<const uint4*>(xb + off0 + 128 + coff);
            }
            if (km > 1) {
                a1 = *reinterpret_cast<const uint4*>(xb + off1 + coff);
                b1 = *reinterpret_cast<const uint4*>(xb + off1 + 128 + coff);
            }
            if (km > 0) proc_pk(a0, b0, s0 < deg, u, acc);
            if (km > 2) {       // issue chunk 2 under chunk-1 compute
                a0 = *reinterpret_cast<const uint4*>(xb + off2 + coff);
                b0 = *reinterpret_cast<const uint4*>(xb + off2 + 128 + coff);
            }
            if (km > 1) proc_pk(a1, b1, s1 < deg, u, acc);
            if (km > 3) {
                a1 = *reinterpret_cast<const uint4*>(xb + off3 + coff);
                b1 = *reinterpret_cast<const uint4*>(xb + off3 + 128 + coff);
            }
            if (km > 2) proc_pk(a0, b0, s2 < deg, u, acc);
            if (km > 3) proc_pk(a1, b1, s3 < deg, u, acc);
            for (int k = 4; k < km; ++k) {   // tail (deg>16, ~46% of nodes)
                int s  = 4 * k + sl;
                int off = nid(s < deg ? s : 0) << 8;
                uint4 a = *reinterpret_cast<const uint4*>(xb + off + coff);
                uint4 b = *reinterpret_cast<const uint4*>(xb + off + 128 + coff);
                proc_pk(a, b, s < deg, u, acc);
            }

            // reduce across the 4 slots of each half (lane bits 3..4 only)
            #pragma unroll
            for (int j = 0; j < DPC; ++j) {
                acc[j] += __shfl_xor(acc[j], 8);
                acc[j] += __shfl_xor(acc[j], 16);
            }
            // residual + per-capsule l2norm; xt recomputed from tw,sc
            float s2 = 0.0f;
            #pragma unroll
            for (int q = 0; q < 8; ++q) {
                float xl = bits_lo(tw[q]) * sc;
                float xh = bits_hi(tw[q]) * sc;
                u[2*q]   = acc[2*q]   + xl;
                u[2*q+1] = acc[2*q+1] + xh;
                s2 = fmaf(u[2*q],   u[2*q],   s2);
                s2 = fmaf(u[2*q+1], u[2*q+1], s2);
            }
            float sc2 = __builtin_amdgcn_rsqf(fmaxf(s2, 1e-24f));
            #pragma unroll
            for (int j = 0; j < DPC; ++j) u[j] *= sc2;
        }

        // slot-0 lanes of each half write that node's 512B fp32 row
        if (sl == 0 && (lane < 32 || wrB)) {
            float* dst = u_out + (size_t)t * DF + c * DPC;
            #pragma unroll
            for (int j = 0; j < DPC; j += 4)
                *reinterpret_cast<float4*>(dst + j) =
                    make_float4(u[j], u[j+1], u[j+2], u[j+3]);
        }
    }
}

extern "C" void kernel_launch(void* const* d_in, const int* in_sizes, int n_in,
                              void* d_out, int out_size, void* d_ws, size_t ws_size,
                              hipStream_t stream) {
    const void* x  = d_in[0];
    const int*  ei = (const int*)d_in[1];
    const int n_nodes = in_sizes[0] / DF;        // 50000
    const int n_edges = in_sizes[1] / 2;         // 800000
    const size_t NC = (size_t)n_nodes * DF;

    // ws layout: xcb bf16 [12.8MB] | slot rows [6.4MB] | flags | cnt [<=6.4MB]
    unsigned char* p = (unsigned char*)d_ws;
    unsigned int*   xcb  = (unsigned int*)p;   p += NC * 2;
    unsigned short* rows = (unsigned short*)p; p += (size_t)n_nodes * KCAP * 2;
    int*            flags = (int*)p;           p += 128;
    int*            cnt  = (int*)p;
    size_t used  = (size_t)(p - (unsigned char*)d_ws);
    size_t avail = (ws_size > used) ? (ws_size - used) : 0;
    int cstr = 32;  // ints between counts: 128B = atomic-only line per node
    while (cstr > 1 && (size_t)n_nodes * cstr * sizeof(int) > avail) cstr >>= 1;
    int zwords = n_nodes * cstr;

    float* u_out = (float*)d_out;

    k_detect_zero<<<NB_ZERO, 256, 0, stream>>>(
        (const unsigned int*)x, (const unsigned int*)ei, flags, cnt, zwords);
    k_prep<<<NB_PREP, 256, 0, stream>>>(x, xcb, ei, cnt, cstr, rows, flags,
                                        n_nodes, n_edges);
    k_route<<<NB_ROUTE, 256, 0, stream>>>(rows, xcb, cnt, cstr, u_out, n_nodes);
}

// Round 7
// 252.791 us; speedup vs baseline: 1.6136x; 1.6136x over previous
//
#include <hip/hip_runtime.h>
#include <hip/hip_bf16.h>

#define DF   128      // feature dim
#define DPC  16       // dims per capsule (8 caps)
#define KCAP 64       // slots per 128B row (count lives in separate cnt array)
#define RWU  64       // ushorts per slot row
#define WPB  4        // waves per 256-thread route block

#define NB_PREP  2048 // persistent prep WGs (fused xc + bucket)
#define NB_ZERO  64   // detect (1) + cnt zeroing (63)

// ---------- helpers ----------
__device__ __forceinline__ float cap_sum(float v) {   // sum over lanes l..l|7
    v += __shfl_xor(v, 1);
    v += __shfl_xor(v, 2);
    v += __shfl_xor(v, 4);
    return v;
}
__device__ __forceinline__ float bits_lo(unsigned int w) {
    union { unsigned int u; float f; } c; c.u = w << 16; return c.f;
}
__device__ __forceinline__ float bits_hi(unsigned int w) {
    union { unsigned int u; float f; } c; c.u = w & 0xFFFF0000u; return c.f;
}
__device__ __forceinline__ unsigned int f2b_pack(float lo, float hi) {
    __hip_bfloat16 a = __float2bfloat16(lo), b = __float2bfloat16(hi);
    unsigned short ua = *reinterpret_cast<unsigned short*>(&a);
    unsigned short ub = *reinterpret_cast<unsigned short*>(&b);
    return ((unsigned int)ub << 16) | ua;
}
__device__ __forceinline__ float2 load_x2(const void* __restrict__ xraw, int fp32,
                                          int node, int lane) {
    size_t off = (size_t)node * DF + (size_t)lane * 2;
    if (fp32) {
        return *reinterpret_cast<const float2*>((const float*)xraw + off);
    } else {
        unsigned int w = ((const unsigned int*)xraw)[(size_t)node * 64 + lane];
        return make_float2(bits_lo(w), bits_hi(w));
    }
}
// per-chunk routing math on PACKED bf16 words (each word unpacked twice ->
// 16 fewer live VGPRs than materializing z[16]; r4 verified numerics are
// bit-identical to the cvt16 version since op order is unchanged).
__device__ __forceinline__ void proc_pk(const uint4& w0, const uint4& w1,
                                        bool valid, const float* u, float* acc) {
    unsigned ww[8] = {w0.x, w0.y, w0.z, w0.w, w1.x, w1.y, w1.z, w1.w};
    float p = 0.0f;
    #pragma unroll
    for (int q = 0; q < 8; ++q) {
        p = fmaf(bits_lo(ww[q]), u[2*q],   p);
        p = fmaf(bits_hi(ww[q]), u[2*q+1], p);
    }
    float ex = __expf(p);
    float sd = ex;
    sd += __shfl_xor(sd, 1);
    sd += __shfl_xor(sd, 2);
    sd += __shfl_xor(sd, 4);
    float w = valid ? ex * __builtin_amdgcn_rcpf(sd) : 0.0f;
    #pragma unroll
    for (int q = 0; q < 8; ++q) {
        acc[2*q]   = fmaf(w, bits_lo(ww[q]), acc[2*q]);
        acc[2*q+1] = fmaf(w, bits_hi(ww[q]), acc[2*q+1]);
    }
}

// ---------- 1: detect dtypes (block 0) + zero cnt array (blocks 1..) --------
__global__ void k_detect_zero(const unsigned int* __restrict__ xw,
                              const unsigned int* __restrict__ ew,
                              int* __restrict__ flags, int* __restrict__ cnt,
                              int zwords) {
    if (blockIdx.x == 0) {
        __shared__ int s_nan, s_zero;
        int tid = threadIdx.x;
        if (tid == 0) { s_nan = 0; s_zero = 0; }
        __syncthreads();
        int cnt_nan = 0;
        for (int i = tid; i < 4096; i += 256) {       // P(fp32 miss) ~ e^-16
            unsigned int lo = xw[i] & 0xFFFFu;
            if ((lo & 0x7F80u) == 0x7F80u) cnt_nan++; // impossible in bf16 data
        }
        int cnt_zero = 0;
        for (int i = tid; i < 1024; i += 256) {
            if (ew[2 * i + 1] == 0u) cnt_zero++;      // int64 high words zero
        }
        atomicAdd(&s_nan, cnt_nan);
        atomicAdd(&s_zero, cnt_zero);
        __syncthreads();
        if (tid == 0) {
            flags[0] = (s_nan > 0) ? 1 : 0;   // x is fp32
            flags[1] = (s_zero > 512) ? 1 : 0; // edge_index is int64
        }
    } else {
        int stride = (NB_ZERO - 1) * 256;
        for (int i = (blockIdx.x - 1) * 256 + threadIdx.x; i < zwords; i += stride)
            cnt[i] = 0;
    }
}

// ---------- 2: FUSED xc(bf16, swizzled) + bucketing -------------------------
// Round-7 change: slot writes are NON-TEMPORAL. Theory under test: the edge
// phase's ~100us is dominated by write-allocate fills -- each random 2B store
// forces the local XCD L2 to fetch the 128B line (~100MB of fills) and then
// bounce dirty ownership between XCDs (deg~16 stores per line from 8 XCDs).
// nt stores bypass L2 allocation and merge byte-enabled at the LLC: no fill,
// no ownership migration. Visibility to the later k_route is guaranteed at
// the kernel boundary. One atomicAdd per edge (r4 proved 2 LLC ops regress).
// xc row (256 B): words [0,32) = caps' dims 0..7, words [32,64) = dims 8..15.
__global__ void k_prep(const void* __restrict__ xraw, unsigned int* __restrict__ xcb,
                       const int* __restrict__ ei,
                       int* __restrict__ cnt, int cstr,
                       unsigned short* __restrict__ rows,
                       const int* __restrict__ flags,
                       int n_nodes, int n_edges) {
    const int fp32 = flags[0];
    const int lane = threadIdx.x & 63;
    const int gw   = (blockIdx.x * blockDim.x + threadIdx.x) >> 6;
    const int nw   = (gridDim.x * blockDim.x) >> 6;
    for (int wid = gw; wid < n_nodes; wid += nw) {
        float2 v = load_x2(xraw, fp32, wid, lane);
        float ss = cap_sum(v.x * v.x + v.y * v.y);
        float scale = 1.0f / fmaxf(sqrtf(ss), 1e-12f);
        int cc = lane >> 3, jp = lane & 7;
        int w = (jp < 4) ? (cc * 4 + jp) : (32 + cc * 4 + (jp - 4));
        xcb[(size_t)wid * 64 + w] = f2b_pack(v.x * scale, v.y * scale);
    }

    const int i64 = flags[1];
    const int gtid = blockIdx.x * blockDim.x + threadIdx.x;
    const int gth  = gridDim.x * blockDim.x;
    for (int e = gtid; e < n_edges; e += gth) {
        int s, t;
        if (i64) {   // coalesced 8B loads, keep low words
            s = (int)((const long long*)ei)[e];
            t = (int)((const long long*)ei)[(size_t)n_edges + e];
        } else {
            s = ei[e]; t = ei[(size_t)n_edges + e];
        }
        if ((unsigned)s < (unsigned)n_nodes && (unsigned)t < (unsigned)n_nodes) {
            int slot = atomicAdd(cnt + (size_t)t * cstr, 1);
            if (slot < KCAP)
                __builtin_nontemporal_store(
                    (unsigned short)s, rows + (size_t)t * KCAP + slot);
        }
    }
}

// ---------- 3: fused 3-iteration routing ----------
// ROUND-7 = the proven r1 structure (best route measured: 108us), restored
// verbatim except: (a) packed tw[] target row (r4-verified identical
// numerics, -8 live regs), (b) the register chunk-cache holds TWO chunks
// (16 edges) instead of three -- r1's third chunk is what overflowed the
// 64-VGPR tier and spilled ~42MB to HBM. Chunks >=2 stream per iteration
// from the LLC-resident xcb. NO waves_per_eu, NO launch-bounds games, NO
// register-pinning asm (r3/r6 post-mortems: those caused scratch explosions).
// One wave per node, non-persistent 12500-WG grid (r1's exact config).
// Lane = e8*8 + c: 8 edge slots x 8 capsules.
__global__ void __launch_bounds__(256)
k_route(const unsigned short* __restrict__ rows,
        const unsigned int* __restrict__ xcb,
        const int* __restrict__ cnt, int cstr,
        float* __restrict__ u_out, int n_nodes) {
    int t    = (blockIdx.x * blockDim.x + threadIdx.x) >> 6;
    int lane = threadIdx.x & 63;
    if (t >= n_nodes) return;
    const int e8 = lane >> 3;
    const int c  = lane & 7;
    const int coff = c * 16;     // byte offset within each 128 B half
    const char* __restrict__ xb = (const char*)xcb;

    // one coalesced line: 64 slot ushorts (32 dwords, replicated wave halves)
    unsigned rw = ((const unsigned*)(rows + (size_t)t * RWU))[lane & 31];

    // target row + degree issued while the row load is in flight
    size_t trow = (size_t)t << 8;
    uint4 t0 = *reinterpret_cast<const uint4*>(xb + trow + coff);
    uint4 t1 = *reinterpret_cast<const uint4*>(xb + trow + 128 + coff);
    int deg = cnt[(size_t)t * cstr];           // same addr -> broadcast load
    deg = __builtin_amdgcn_readfirstlane(deg);
    deg = min(deg, KCAP);

    // slot s ushort: dword s>>1 of the row, half-sel s&1, via shfl
    auto nid = [&](int s) -> int {
        unsigned wv = __shfl(rw, (lane & 32) | (s >> 1));
        return (int)((s & 1) ? (wv >> 16) : (wv & 0xFFFFu));
    };
    auto ldc = [&](int k, uint4& a, uint4& b) {  // chunk k's 32 B for lane
        int s  = e8 + 8 * k;
        int sl = (s < deg) ? s : 0;              // clamp: dummy slot 0
        int off = nid(sl) << 8;
        a = *reinterpret_cast<const uint4*>(xb + off + coff);
        b = *reinterpret_cast<const uint4*>(xb + off + 128 + coff);
    };

    // cache chunks 0,1 in registers (16 VGPRs) across all 3 iterations
    uint4 k0a, k0b, k1a, k1b;
    if (deg > 0) ldc(0, k0a, k0b);
    if (deg > 8) ldc(1, k1a, k1b);

    // normalize target capsule while loads fly (packed tw[] + sc)
    unsigned tw[8] = {t0.x, t0.y, t0.z, t0.w, t1.x, t1.y, t1.z, t1.w};
    float ss = 0.0f;
    #pragma unroll
    for (int q = 0; q < 8; ++q) {
        float xl = bits_lo(tw[q]), xh = bits_hi(tw[q]);
        ss = fmaf(xl, xl, ss);
        ss = fmaf(xh, xh, ss);
    }
    float sc = __builtin_amdgcn_rsqf(fmaxf(ss, 1e-24f));
    float u[DPC];
    #pragma unroll
    for (int q = 0; q < 8; ++q) {
        u[2*q]   = bits_lo(tw[q]) * sc;
        u[2*q+1] = bits_hi(tw[q]) * sc;
    }

    for (int it = 0; it < 3; ++it) {
        float acc[DPC];
        #pragma unroll
        for (int j = 0; j < DPC; ++j) acc[j] = 0.0f;

        if (deg > 0) proc_pk(k0a, k0b, e8 < deg,     u, acc);
        if (deg > 8) proc_pk(k1a, k1b, 8 + e8 < deg, u, acc);
        for (int base = 16; base < deg; base += 8) { // stream (deg>16: ~46%)
            int s  = base + e8;
            int sl = (s < deg) ? s : 0;
            int off = nid(sl) << 8;
            uint4 a = *reinterpret_cast<const uint4*>(xb + off + coff);
            uint4 b = *reinterpret_cast<const uint4*>(xb + off + 128 + coff);
            proc_pk(a, b, s < deg, u, acc);
        }

        // reduce across the 8 edge slots (lane bits 3..5)
        #pragma unroll
        for (int j = 0; j < DPC; ++j) {
            acc[j] += __shfl_xor(acc[j], 8);
            acc[j] += __shfl_xor(acc[j], 16);
            acc[j] += __shfl_xor(acc[j], 32);
        }
        // residual + per-capsule l2norm; xt recomputed from tw,sc
        float s2 = 0.0f;
        #pragma unroll
        for (int q = 0; q < 8; ++q) {
            float xl = bits_lo(tw[q]) * sc;
            float xh = bits_hi(tw[q]) * sc;
            u[2*q]   = acc[2*q]   + xl;
            u[2*q+1] = acc[2*q+1] + xh;
            s2 = fmaf(u[2*q],   u[2*q],   s2);
            s2 = fmaf(u[2*q+1], u[2*q+1], s2);
        }
        float sc2 = __builtin_amdgcn_rsqf(fmaxf(s2, 1e-24f));
        #pragma unroll
        for (int j = 0; j < DPC; ++j) u[j] *= sc2;
    }

    if (e8 == 0) {   // lanes 0..7 cover the full 512 B fp32 output row
        float* dst = u_out + (size_t)t * DF + c * DPC;
        #pragma unroll
        for (int j = 0; j < DPC; j += 4)
            *reinterpret_cast<float4*>(dst + j) =
                make_float4(u[j], u[j+1], u[j+2], u[j+3]);
    }
}

extern "C" void kernel_launch(void* const* d_in, const int* in_sizes, int n_in,
                              void* d_out, int out_size, void* d_ws, size_t ws_size,
                              hipStream_t stream) {
    const void* x  = d_in[0];
    const int*  ei = (const int*)d_in[1];
    const int n_nodes = in_sizes[0] / DF;        // 50000
    const int n_edges = in_sizes[1] / 2;         // 800000
    const size_t NC = (size_t)n_nodes * DF;

    // ws layout: xcb bf16 [12.8MB] | slot rows [6.4MB] | flags | cnt [<=6.4MB]
    unsigned char* p = (unsigned char*)d_ws;
    unsigned int*   xcb  = (unsigned int*)p;   p += NC * 2;
    unsigned short* rows = (unsigned short*)p; p += (size_t)n_nodes * KCAP * 2;
    int*            flags = (int*)p;           p += 128;
    int*            cnt  = (int*)p;
    size_t used  = (size_t)(p - (unsigned char*)d_ws);
    size_t avail = (ws_size > used) ? (ws_size - used) : 0;
    int cstr = 32;  // ints between counts: 128B = atomic-only line per node
    while (cstr > 1 && (size_t)n_nodes * cstr * sizeof(int) > avail) cstr >>= 1;
    int zwords = n_nodes * cstr;

    float* u_out = (float*)d_out;

    const int nb_route = (n_nodes + WPB - 1) / WPB;   // 12500, 1 wave/node

    k_detect_zero<<<NB_ZERO, 256, 0, stream>>>(
        (const unsigned int*)x, (const unsigned int*)ei, flags, cnt, zwords);
    k_prep<<<NB_PREP, 256, 0, stream>>>(x, xcb, ei, cnt, cstr, rows, flags,
                                        n_nodes, n_edges);
    k_route<<<nb_route, 256, 0, stream>>>(rows, xcb, cnt, cstr, u_out, n_nodes);
}

// Round 8
// 240.972 us; speedup vs baseline: 1.6928x; 1.0490x over previous
//
#include <hip/hip_runtime.h>
#include <hip/hip_bf16.h>

#define DF   128      // feature dim
#define DPC  16       // dims per capsule (8 caps)
#define KCAP 64       // slots per 128B row (count lives in separate cnt array)
#define RWU  64       // ushorts per slot row
#define WPB  4        // waves per 256-thread route block
#define NXCD 8        // XCDs on MI355X
#define PCAP 16       // per-XCD slot cap (multinomial overflow P ~ 1e-10)

#define NB_PREP  2048 // persistent prep WGs (fused xc + bucket)
#define NB_CMP   2048 // compact WGs
#define NB_ZERO  257  // detect (1) + zeroing (256)

// ---------- helpers ----------
__device__ __forceinline__ float cap_sum(float v) {   // sum over lanes l..l|7
    v += __shfl_xor(v, 1);
    v += __shfl_xor(v, 2);
    v += __shfl_xor(v, 4);
    return v;
}
__device__ __forceinline__ float bits_lo(unsigned int w) {
    union { unsigned int u; float f; } c; c.u = w << 16; return c.f;
}
__device__ __forceinline__ float bits_hi(unsigned int w) {
    union { unsigned int u; float f; } c; c.u = w & 0xFFFF0000u; return c.f;
}
__device__ __forceinline__ unsigned int f2b_pack(float lo, float hi) {
    __hip_bfloat16 a = __float2bfloat16(lo), b = __float2bfloat16(hi);
    unsigned short ua = *reinterpret_cast<unsigned short*>(&a);
    unsigned short ub = *reinterpret_cast<unsigned short*>(&b);
    return ((unsigned int)ub << 16) | ua;
}
__device__ __forceinline__ float2 load_x2(const void* __restrict__ xraw, int fp32,
                                          int node, int lane) {
    size_t off = (size_t)node * DF + (size_t)lane * 2;
    if (fp32) {
        return *reinterpret_cast<const float2*>((const float*)xraw + off);
    } else {
        unsigned int w = ((const unsigned int*)xraw)[(size_t)node * 64 + lane];
        return make_float2(bits_lo(w), bits_hi(w));
    }
}
// per-chunk routing math on PACKED bf16 words (r4-verified numerics identical
// to the cvt16 version: op order unchanged, 16 fewer live VGPRs).
__device__ __forceinline__ void proc_pk(const uint4& w0, const uint4& w1,
                                        bool valid, const float* u, float* acc) {
    unsigned ww[8] = {w0.x, w0.y, w0.z, w0.w, w1.x, w1.y, w1.z, w1.w};
    float p = 0.0f;
    #pragma unroll
    for (int q = 0; q < 8; ++q) {
        p = fmaf(bits_lo(ww[q]), u[2*q],   p);
        p = fmaf(bits_hi(ww[q]), u[2*q+1], p);
    }
    float ex = __expf(p);
    float sd = ex;
    sd += __shfl_xor(sd, 1);
    sd += __shfl_xor(sd, 2);
    sd += __shfl_xor(sd, 4);
    float w = valid ? ex * __builtin_amdgcn_rcpf(sd) : 0.0f;
    #pragma unroll
    for (int q = 0; q < 8; ++q) {
        acc[2*q]   = fmaf(w, bits_lo(ww[q]), acc[2*q]);
        acc[2*q+1] = fmaf(w, bits_hi(ww[q]), acc[2*q+1]);
    }
}

// ---------- 1: detect dtypes (block 0) + zero a region (blocks 1..) ---------
// r7 lesson: 63 scalar-store WGs zeroing 6.4MB cost ~30us. Now: 256 WGs,
// uint4 stores, and the main path only needs cnt8 zeroed (1.6MB).
__global__ void k_detect_zero(const unsigned int* __restrict__ xw,
                              const unsigned int* __restrict__ ew,
                              int* __restrict__ flags,
                              uint4* __restrict__ zptr, int zquads) {
    if (blockIdx.x == 0) {
        __shared__ int s_nan, s_zero;
        int tid = threadIdx.x;
        if (tid == 0) { s_nan = 0; s_zero = 0; }
        __syncthreads();
        int cnt_nan = 0;
        for (int i = tid; i < 4096; i += 256) {       // P(fp32 miss) ~ e^-16
            unsigned int lo = xw[i] & 0xFFFFu;
            if ((lo & 0x7F80u) == 0x7F80u) cnt_nan++; // impossible in bf16 data
        }
        int cnt_zero = 0;
        for (int i = tid; i < 1024; i += 256) {
            if (ew[2 * i + 1] == 0u) cnt_zero++;      // int64 high words zero
        }
        atomicAdd(&s_nan, cnt_nan);
        atomicAdd(&s_zero, cnt_zero);
        __syncthreads();
        if (tid == 0) {
            flags[0] = (s_nan > 0) ? 1 : 0;   // x is fp32
            flags[1] = (s_zero > 512) ? 1 : 0; // edge_index is int64
        }
    } else {
        int stride = (NB_ZERO - 1) * 256;
        for (int i = (blockIdx.x - 1) * 256 + threadIdx.x; i < zquads; i += stride)
            zptr[i] = make_uint4(0u, 0u, 0u, 0u);
    }
}

// ---------- 2-main: fused xc + XCD-PRIVATIZED bucketing ---------------------
// Round-8 hypothesis test. All device-scope variants (r0-r7) pinned prep at
// ~100us => the LLC atomic path itself (~8-9 G ops/s for random lines) is the
// wall, not line-ownership details. Fix: per-XCD private copies indexed by
// the PHYSICAL xcc_id (s_getreg HW_REG_XCC_ID, HW-verified on MI355X), with
// WORKGROUP-scope atomics -> compiler drops sc1 -> the RMW executes in the
// issuing XCD's private L2 (~200cy, high throughput, zero cross-XCD traffic).
// Correctness needs only XCD-level atomicity: each copy is touched by exactly
// one XCD (the L2 is that XCD's coherence point). Slot stores also land in
// the local L2. k_compact merges afterwards; kernel-boundary writeback(+acq)
// makes everything visible (same mechanism rows/cnt relied on in r5-r7).
__global__ void k_prep(const void* __restrict__ xraw, unsigned int* __restrict__ xcb,
                       const int* __restrict__ ei,
                       int* __restrict__ cnt8,
                       unsigned short* __restrict__ rows8,
                       const int* __restrict__ flags,
                       int n_nodes, int n_edges) {
    const int fp32 = flags[0];
    const int lane = threadIdx.x & 63;
    const int gw   = (blockIdx.x * blockDim.x + threadIdx.x) >> 6;
    const int nw   = (gridDim.x * blockDim.x) >> 6;
    for (int wid = gw; wid < n_nodes; wid += nw) {
        float2 v = load_x2(xraw, fp32, wid, lane);
        float ss = cap_sum(v.x * v.x + v.y * v.y);
        float scale = 1.0f / fmaxf(sqrtf(ss), 1e-12f);
        int cc = lane >> 3, jp = lane & 7;
        int w = (jp < 4) ? (cc * 4 + jp) : (32 + cc * 4 + (jp - 4));
        xcb[(size_t)wid * 64 + w] = f2b_pack(v.x * scale, v.y * scale);
    }

    // physical XCD id: hwreg 20 (XCC_ID), offset 0, size 4 -> imm 6164
    unsigned xcd = __builtin_amdgcn_s_getreg((3 << 11) | 20) & (NXCD - 1);
    int*            mycnt  = cnt8 + (size_t)xcd * n_nodes;
    unsigned short* myrows = rows8 + (size_t)xcd * n_nodes * PCAP;

    const int i64 = flags[1];
    const int gtid = blockIdx.x * blockDim.x + threadIdx.x;
    const int gth  = gridDim.x * blockDim.x;
    for (int e = gtid; e < n_edges; e += gth) {
        int s, t;
        if (i64) {   // coalesced 8B loads, keep low words
            s = (int)((const long long*)ei)[e];
            t = (int)((const long long*)ei)[(size_t)n_edges + e];
        } else {
            s = ei[e]; t = ei[(size_t)n_edges + e];
        }
        if ((unsigned)s < (unsigned)n_nodes && (unsigned)t < (unsigned)n_nodes) {
            int slot = __hip_atomic_fetch_add(&mycnt[t], 1, __ATOMIC_RELAXED,
                                              __HIP_MEMORY_SCOPE_WORKGROUP);
            if (slot < PCAP)
                myrows[(size_t)t * PCAP + slot] = (unsigned short)s;
        }
    }
}

// ---------- 2-fallback: r7's prep (device-scope), used if ws too small ------
__global__ void k_prep_fb(const void* __restrict__ xraw, unsigned int* __restrict__ xcb,
                          const int* __restrict__ ei,
                          int* __restrict__ cnt, int cstr,
                          unsigned short* __restrict__ rows,
                          const int* __restrict__ flags,
                          int n_nodes, int n_edges) {
    const int fp32 = flags[0];
    const int lane = threadIdx.x & 63;
    const int gw   = (blockIdx.x * blockDim.x + threadIdx.x) >> 6;
    const int nw   = (gridDim.x * blockDim.x) >> 6;
    for (int wid = gw; wid < n_nodes; wid += nw) {
        float2 v = load_x2(xraw, fp32, wid, lane);
        float ss = cap_sum(v.x * v.x + v.y * v.y);
        float scale = 1.0f / fmaxf(sqrtf(ss), 1e-12f);
        int cc = lane >> 3, jp = lane & 7;
        int w = (jp < 4) ? (cc * 4 + jp) : (32 + cc * 4 + (jp - 4));
        xcb[(size_t)wid * 64 + w] = f2b_pack(v.x * scale, v.y * scale);
    }
    const int i64 = flags[1];
    const int gtid = blockIdx.x * blockDim.x + threadIdx.x;
    const int gth  = gridDim.x * blockDim.x;
    for (int e = gtid; e < n_edges; e += gth) {
        int s, t;
        if (i64) {
            s = (int)((const long long*)ei)[e];
            t = (int)((const long long*)ei)[(size_t)n_edges + e];
        } else {
            s = ei[e]; t = ei[(size_t)n_edges + e];
        }
        if ((unsigned)s < (unsigned)n_nodes && (unsigned)t < (unsigned)n_nodes) {
            int slot = atomicAdd(cnt + (size_t)t * cstr, 1);
            if (slot < KCAP)
                __builtin_nontemporal_store(
                    (unsigned short)s, rows + (size_t)t * KCAP + slot);
        }
    }
}

// ---------- 2c: merge 8 per-XCD sub-lists into route's rows/cnt layout ------
// Pure streaming (sequential by node, coalesced), ~19MB read + ~7MB write.
// One wave per node: lane l handles dword (l&7) of region (l>>3).
__global__ void k_compact(const int* __restrict__ cnt8,
                          const unsigned short* __restrict__ rows8,
                          int* __restrict__ cnt,
                          unsigned short* __restrict__ rows, int n_nodes) {
    const int lane = threadIdx.x & 63;
    const int r = lane >> 3;          // region (XCD) 0..7
    const int q = lane & 7;           // dword within region (2 ushorts)
    const int gw = (blockIdx.x * blockDim.x + threadIdx.x) >> 6;
    const int nw = (gridDim.x * blockDim.x) >> 6;
    for (int t = gw; t < n_nodes; t += nw) {
        int c = cnt8[(size_t)r * n_nodes + t];    // same addr per 8 lanes
        c = min(c, PCAP);
        int pref = 0, deg = 0;                    // exclusive prefix + total
        #pragma unroll
        for (int y = 0; y < NXCD; ++y) {
            int cy = __shfl(c, y * 8);
            pref += (y < r) ? cy : 0;
            deg  += cy;
        }
        unsigned w = ((const unsigned*)(rows8 + ((size_t)r * n_nodes + t) * PCAP))[q];
        int g0 = pref + 2 * q;
        unsigned short* orow = rows + (size_t)t * RWU;
        if (2 * q     < c && g0     < KCAP) orow[g0]     = (unsigned short)(w & 0xFFFFu);
        if (2 * q + 1 < c && g0 + 1 < KCAP) orow[g0 + 1] = (unsigned short)(w >> 16);
        if (lane == 0) cnt[t] = min(deg, KCAP);
    }
}

// ---------- 3: fused 3-iteration routing ----------
// VERBATIM r7 (measured 109us, VGPR=60, zero spill): r1 structure, packed
// tw[], 2-chunk register cache, stream tail. Do not touch.
__global__ void __launch_bounds__(256)
k_route(const unsigned short* __restrict__ rows,
        const unsigned int* __restrict__ xcb,
        const int* __restrict__ cnt, int cstr,
        float* __restrict__ u_out, int n_nodes) {
    int t    = (blockIdx.x * blockDim.x + threadIdx.x) >> 6;
    int lane = threadIdx.x & 63;
    if (t >= n_nodes) return;
    const int e8 = lane >> 3;
    const int c  = lane & 7;
    const int coff = c * 16;     // byte offset within each 128 B half
    const char* __restrict__ xb = (const char*)xcb;

    // one coalesced line: 64 slot ushorts (32 dwords, replicated wave halves)
    unsigned rw = ((const unsigned*)(rows + (size_t)t * RWU))[lane & 31];

    // target row + degree issued while the row load is in flight
    size_t trow = (size_t)t << 8;
    uint4 t0 = *reinterpret_cast<const uint4*>(xb + trow + coff);
    uint4 t1 = *reinterpret_cast<const uint4*>(xb + trow + 128 + coff);
    int deg = cnt[(size_t)t * cstr];           // same addr -> broadcast load
    deg = __builtin_amdgcn_readfirstlane(deg);
    deg = min(deg, KCAP);

    // slot s ushort: dword s>>1 of the row, half-sel s&1, via shfl
    auto nid = [&](int s) -> int {
        unsigned wv = __shfl(rw, (lane & 32) | (s >> 1));
        return (int)((s & 1) ? (wv >> 16) : (wv & 0xFFFFu));
    };
    auto ldc = [&](int k, uint4& a, uint4& b) {  // chunk k's 32 B for lane
        int s  = e8 + 8 * k;
        int sl = (s < deg) ? s : 0;              // clamp: dummy slot 0
        int off = nid(sl) << 8;
        a = *reinterpret_cast<const uint4*>(xb + off + coff);
        b = *reinterpret_cast<const uint4*>(xb + off + 128 + coff);
    };

    // cache chunks 0,1 in registers (16 VGPRs) across all 3 iterations
    uint4 k0a, k0b, k1a, k1b;
    if (deg > 0) ldc(0, k0a, k0b);
    if (deg > 8) ldc(1, k1a, k1b);

    // normalize target capsule while loads fly (packed tw[] + sc)
    unsigned tw[8] = {t0.x, t0.y, t0.z, t0.w, t1.x, t1.y, t1.z, t1.w};
    float ss = 0.0f;
    #pragma unroll
    for (int q = 0; q < 8; ++q) {
        float xl = bits_lo(tw[q]), xh = bits_hi(tw[q]);
        ss = fmaf(xl, xl, ss);
        ss = fmaf(xh, xh, ss);
    }
    float sc = __builtin_amdgcn_rsqf(fmaxf(ss, 1e-24f));
    float u[DPC];
    #pragma unroll
    for (int q = 0; q < 8; ++q) {
        u[2*q]   = bits_lo(tw[q]) * sc;
        u[2*q+1] = bits_hi(tw[q]) * sc;
    }

    for (int it = 0; it < 3; ++it) {
        float acc[DPC];
        #pragma unroll
        for (int j = 0; j < DPC; ++j) acc[j] = 0.0f;

        if (deg > 0) proc_pk(k0a, k0b, e8 < deg,     u, acc);
        if (deg > 8) proc_pk(k1a, k1b, 8 + e8 < deg, u, acc);
        for (int base = 16; base < deg; base += 8) { // stream (deg>16: ~46%)
            int s  = base + e8;
            int sl = (s < deg) ? s : 0;
            int off = nid(sl) << 8;
            uint4 a = *reinterpret_cast<const uint4*>(xb + off + coff);
            uint4 b = *reinterpret_cast<const uint4*>(xb + off + 128 + coff);
            proc_pk(a, b, s < deg, u, acc);
        }

        // reduce across the 8 edge slots (lane bits 3..5)
        #pragma unroll
        for (int j = 0; j < DPC; ++j) {
            acc[j] += __shfl_xor(acc[j], 8);
            acc[j] += __shfl_xor(acc[j], 16);
            acc[j] += __shfl_xor(acc[j], 32);
        }
        // residual + per-capsule l2norm; xt recomputed from tw,sc
        float s2 = 0.0f;
        #pragma unroll
        for (int q = 0; q < 8; ++q) {
            float xl = bits_lo(tw[q]) * sc;
            float xh = bits_hi(tw[q]) * sc;
            u[2*q]   = acc[2*q]   + xl;
            u[2*q+1] = acc[2*q+1] + xh;
            s2 = fmaf(u[2*q],   u[2*q],   s2);
            s2 = fmaf(u[2*q+1], u[2*q+1], s2);
        }
        float sc2 = __builtin_amdgcn_rsqf(fmaxf(s2, 1e-24f));
        #pragma unroll
        for (int j = 0; j < DPC; ++j) u[j] *= sc2;
    }

    if (e8 == 0) {   // lanes 0..7 cover the full 512 B fp32 output row
        float* dst = u_out + (size_t)t * DF + c * DPC;
        #pragma unroll
        for (int j = 0; j < DPC; j += 4)
            *reinterpret_cast<float4*>(dst + j) =
                make_float4(u[j], u[j+1], u[j+2], u[j+3]);
    }
}

extern "C" void kernel_launch(void* const* d_in, const int* in_sizes, int n_in,
                              void* d_out, int out_size, void* d_ws, size_t ws_size,
                              hipStream_t stream) {
    const void* x  = d_in[0];
    const int*  ei = (const int*)d_in[1];
    const int n_nodes = in_sizes[0] / DF;        // 50000
    const int n_edges = in_sizes[1] / 2;         // 800000
    const size_t NC = (size_t)n_nodes * DF;

    // ws layout: xcb 12.8MB | rows 6.4MB | flags | cnt 200KB | cnt8 1.6MB |
    //            rows8 12.8MB  (~33.9MB total; fallback path if ws smaller)
    unsigned char* p = (unsigned char*)d_ws;
    unsigned int*   xcb   = (unsigned int*)p;   p += NC * 2;
    unsigned short* rows  = (unsigned short*)p; p += (size_t)n_nodes * KCAP * 2;
    int*            flags = (int*)p;            p += 128;
    int*            cnt   = (int*)p;            p += (size_t)n_nodes * 4;
    int*            cnt8  = (int*)p;            p += (size_t)n_nodes * NXCD * 4;
    unsigned short* rows8 = (unsigned short*)p; p += (size_t)n_nodes * NXCD * PCAP * 2;
    size_t need = (size_t)(p - (unsigned char*)d_ws);

    float* u_out = (float*)d_out;
    const int nb_route = (n_nodes + WPB - 1) / WPB;   // 12500, 1 wave/node

    if (ws_size >= need) {
        // main path: XCD-privatized buckets + compact
        int zquads = (n_nodes * NXCD) / 4;            // cnt8 in uint4
        k_detect_zero<<<NB_ZERO, 256, 0, stream>>>(
            (const unsigned int*)x, (const unsigned int*)ei, flags,
            (uint4*)cnt8, zquads);
        k_prep<<<NB_PREP, 256, 0, stream>>>(x, xcb, ei, cnt8, rows8, flags,
                                            n_nodes, n_edges);
        k_compact<<<NB_CMP, 256, 0, stream>>>(cnt8, rows8, cnt, rows, n_nodes);
        k_route<<<nb_route, 256, 0, stream>>>(rows, xcb, cnt, 1, u_out, n_nodes);
    } else {
        // fallback: r7 device-scope path, cnt strided into remaining space
        size_t cnt_off = (size_t)((unsigned char*)cnt - (unsigned char*)d_ws);
        size_t avail = (ws_size > cnt_off) ? ws_size - cnt_off : 0;
        int cstr = 32;
        while (cstr > 1 && (size_t)n_nodes * cstr * sizeof(int) > avail) cstr >>= 1;
        int zquads = (n_nodes * cstr) / 4;
        k_detect_zero<<<NB_ZERO, 256, 0, stream>>>(
            (const unsigned int*)x, (const unsigned int*)ei, flags,
            (uint4*)cnt, zquads);
        k_prep_fb<<<NB_PREP, 256, 0, stream>>>(x, xcb, ei, cnt, cstr, rows,
                                               flags, n_nodes, n_edges);
        k_route<<<nb_route, 256, 0, stream>>>(rows, xcb, cnt, cstr, u_out, n_nodes);
    }
}